// Round 4
// baseline (554.947 us; speedup 1.0000x reference)
//
#include <hip/hip_runtime.h>

// Problem constants
#define KC   1024        // codebook size
#define DD   64          // code dim
#define NR   65536       // total rows (16*4096)

#define DECAY     0.99f
#define ONEM      0.01f
#define EPSV      1e-5f

// d_out layout (floats), in reference return order:
#define OFF_ZQ    0
#define OFF_LOSS  4194304
#define OFF_IDX   4194305
#define OFF_NCB   4259841
#define OFF_NECS  4325377
#define OFF_NEW   4326401

// Scratch aliases inside d_out (zeroed by prep, consumed+overwritten by final):
//   cluster counts  -> OFF_NECS region (1024)
//   cluster sums    -> OFF_NEW region (65536)
//   sum-sq-error    -> OFF_LOSS (1)
//   ||c||^2 table   -> first 1024 floats of OFF_NCB region

__global__ void vq_prep(const float* __restrict__ cb, float* __restrict__ out) {
    int tid = blockIdx.x * blockDim.x + threadIdx.x;
    if (tid < 65536) out[OFF_NEW + tid] = 0.0f;          // cluster sums
    if (tid < 1024) {
        out[OFF_NECS + tid] = 0.0f;                      // cluster counts
        const float* c = cb + tid * 64;
        float s = 0.f;
        #pragma unroll
        for (int d = 0; d < 64; ++d) s += c[d] * c[d];
        out[OFF_NCB + tid] = s;                          // ||c_k||^2
    }
    if (tid == 0) out[OFF_LOSS] = 0.0f;                  // SSE accumulator
}

// 1024 blocks x 512 threads (8 waves). Each block owns 64 rows.
// lane (0..63) = row; wave (0..7) = 128-code chunk.
// z tile lives in LDS (stride 68 floats -> 16B-aligned b128, conflict-free);
// codebook addresses are wave-uniform -> s_load_dwordx4 broadcast.
// Per d-subtile: 1 ds_read_b128 + 8 s_load_dwordx4 feed 32 v_fmac.
// argmin uses score = ||c||^2 - 2*z.c (zz constant over k -> same argmin).
__global__ __launch_bounds__(512, 8) void vq_main(const float* __restrict__ z,
                                                  const float* __restrict__ cb,
                                                  const float* __restrict__ cc,
                                                  float* __restrict__ out) {
    const int lane = threadIdx.x & 63;
    const int wid  = threadIdx.x >> 6;
    const int t    = threadIdx.x;

    __shared__ float s_zs[64 * 68];          // [row][d], stride 68 (17.4 KB)
    __shared__ float s_dist[8][64];
    __shared__ int   s_idx [8][64];
    __shared__ int   s_final[64];
    __shared__ float s_red[512];

    // Stage z tile: 2 float4s per thread, ds_write_b128, conflict-free.
    const float4* zb4 = reinterpret_cast<const float4*>(z) + (size_t)blockIdx.x * 1024;
    #pragma unroll
    for (int j = 0; j < 2; ++j) {
        const int f = t + 512 * j;           // float4 index in 64x64 tile
        const float4 v = zb4[f];
        const int r  = f >> 4;
        const int d0 = (f & 15) * 4;
        *reinterpret_cast<float4*>(&s_zs[r * 68 + d0]) = v;
    }
    __syncthreads();

    // Wave-uniform code-chunk base in an SGPR.
    const int kbase = __builtin_amdgcn_readfirstlane(wid) * 128;

    float bestd = 3.4e38f;
    int   bestk = kbase;
    for (int k0 = kbase; k0 < kbase + 128; k0 += 8) {
        const float* c0 = cb + (size_t)k0 * 64;
        float a0 = 0.f, a1 = 0.f, a2 = 0.f, a3 = 0.f;
        float a4 = 0.f, a5 = 0.f, a6 = 0.f, a7 = 0.f;
        #pragma unroll
        for (int dt = 0; dt < 16; ++dt) {
            const float4 zv = *reinterpret_cast<const float4*>(&s_zs[lane * 68 + dt * 4]);
            const float4 c0v = *reinterpret_cast<const float4*>(c0 + 0 * 64 + dt * 4);
            const float4 c1v = *reinterpret_cast<const float4*>(c0 + 1 * 64 + dt * 4);
            const float4 c2v = *reinterpret_cast<const float4*>(c0 + 2 * 64 + dt * 4);
            const float4 c3v = *reinterpret_cast<const float4*>(c0 + 3 * 64 + dt * 4);
            const float4 c4v = *reinterpret_cast<const float4*>(c0 + 4 * 64 + dt * 4);
            const float4 c5v = *reinterpret_cast<const float4*>(c0 + 5 * 64 + dt * 4);
            const float4 c6v = *reinterpret_cast<const float4*>(c0 + 6 * 64 + dt * 4);
            const float4 c7v = *reinterpret_cast<const float4*>(c0 + 7 * 64 + dt * 4);
            a0 = fmaf(zv.x, c0v.x, a0); a0 = fmaf(zv.y, c0v.y, a0);
            a0 = fmaf(zv.z, c0v.z, a0); a0 = fmaf(zv.w, c0v.w, a0);
            a1 = fmaf(zv.x, c1v.x, a1); a1 = fmaf(zv.y, c1v.y, a1);
            a1 = fmaf(zv.z, c1v.z, a1); a1 = fmaf(zv.w, c1v.w, a1);
            a2 = fmaf(zv.x, c2v.x, a2); a2 = fmaf(zv.y, c2v.y, a2);
            a2 = fmaf(zv.z, c2v.z, a2); a2 = fmaf(zv.w, c2v.w, a2);
            a3 = fmaf(zv.x, c3v.x, a3); a3 = fmaf(zv.y, c3v.y, a3);
            a3 = fmaf(zv.z, c3v.z, a3); a3 = fmaf(zv.w, c3v.w, a3);
            a4 = fmaf(zv.x, c4v.x, a4); a4 = fmaf(zv.y, c4v.y, a4);
            a4 = fmaf(zv.z, c4v.z, a4); a4 = fmaf(zv.w, c4v.w, a4);
            a5 = fmaf(zv.x, c5v.x, a5); a5 = fmaf(zv.y, c5v.y, a5);
            a5 = fmaf(zv.z, c5v.z, a5); a5 = fmaf(zv.w, c5v.w, a5);
            a6 = fmaf(zv.x, c6v.x, a6); a6 = fmaf(zv.y, c6v.y, a6);
            a6 = fmaf(zv.z, c6v.z, a6); a6 = fmaf(zv.w, c6v.w, a6);
            a7 = fmaf(zv.x, c7v.x, a7); a7 = fmaf(zv.y, c7v.y, a7);
            a7 = fmaf(zv.z, c7v.z, a7); a7 = fmaf(zv.w, c7v.w, a7);
        }
        // score = ||c||^2 - 2*dot; ascending code order, strict < (first-min).
        const float s0 = fmaf(-2.f, a0, cc[k0 + 0]);
        const float s1 = fmaf(-2.f, a1, cc[k0 + 1]);
        const float s2 = fmaf(-2.f, a2, cc[k0 + 2]);
        const float s3 = fmaf(-2.f, a3, cc[k0 + 3]);
        const float s4 = fmaf(-2.f, a4, cc[k0 + 4]);
        const float s5 = fmaf(-2.f, a5, cc[k0 + 5]);
        const float s6 = fmaf(-2.f, a6, cc[k0 + 6]);
        const float s7 = fmaf(-2.f, a7, cc[k0 + 7]);
        if (s0 < bestd) { bestd = s0; bestk = k0 + 0; }
        if (s1 < bestd) { bestd = s1; bestk = k0 + 1; }
        if (s2 < bestd) { bestd = s2; bestk = k0 + 2; }
        if (s3 < bestd) { bestd = s3; bestk = k0 + 3; }
        if (s4 < bestd) { bestd = s4; bestk = k0 + 4; }
        if (s5 < bestd) { bestd = s5; bestk = k0 + 5; }
        if (s6 < bestd) { bestd = s6; bestk = k0 + 6; }
        if (s7 < bestd) { bestd = s7; bestk = k0 + 7; }
    }

    s_dist[wid][lane] = bestd;
    s_idx [wid][lane] = bestk;
    __syncthreads();

    if (wid == 0) {
        float bd = s_dist[0][lane];
        int   bk = s_idx [0][lane];
        #pragma unroll
        for (int w = 1; w < 8; ++w) {
            const float dw = s_dist[w][lane];
            if (dw < bd) { bd = dw; bk = s_idx[w][lane]; }  // waves ascend in code space
        }
        s_final[lane] = bk;
        const int row = blockIdx.x * 64 + lane;
        out[OFF_IDX + row] = (float)bk;
        atomicAdd(&out[OFF_NECS + bk], 1.0f);               // cluster count
    }
    __syncthreads();

    // Phase 2: coalesced z_q write + commitment SSE + cluster-sum atomics.
    float sse = 0.f;
    float4* qb = reinterpret_cast<float4*>(out + OFF_ZQ) + (size_t)blockIdx.x * 1024;
    const float4* cb4 = reinterpret_cast<const float4*>(cb);
    #pragma unroll
    for (int j = 0; j < 2; ++j) {
        const int f  = t + 512 * j;     // float4 index in block tile
        const int r  = f >> 4;          // row within tile
        const int fc = f & 15;          // float4 within row
        const int gk = s_final[r];
        const float4 zv = *reinterpret_cast<const float4*>(&s_zs[r * 68 + fc * 4]);
        const float4 cv = cb4[gk * 16 + fc];
        qb[f] = cv;                     // z_q_st == z_q numerically
        const float e0 = zv.x - cv.x, e1 = zv.y - cv.y;
        const float e2 = zv.z - cv.z, e3 = zv.w - cv.w;
        sse += e0*e0 + e1*e1 + e2*e2 + e3*e3;
        float* sp = out + OFF_NEW + gk * 64 + fc * 4;
        atomicAdd(sp + 0, zv.x);
        atomicAdd(sp + 1, zv.y);
        atomicAdd(sp + 2, zv.z);
        atomicAdd(sp + 3, zv.w);
    }

    s_red[t] = sse;
    __syncthreads();
    for (int off = 256; off > 0; off >>= 1) {
        if (t < off) s_red[t] += s_red[t + off];
        __syncthreads();
    }
    if (t == 0) atomicAdd(&out[OFF_LOSS], s_red[0]);
}

// One block, 1024 threads: EMA update + normalization + loss finalize.
__global__ __launch_bounds__(1024) void vq_final(const float* __restrict__ ema_cs,
                                                 const float* __restrict__ ema_w,
                                                 float* __restrict__ out) {
    const int k = threadIdx.x;
    const float cnt  = out[OFF_NECS + k];
    const float necs = DECAY * ema_cs[k] + ONEM * cnt;

    __shared__ float s_red[1024];
    __shared__ float s_den[1024];
    s_red[k] = necs;
    __syncthreads();
    for (int off = 512; off > 0; off >>= 1) {
        if (k < off) s_red[k] += s_red[k + off];
        __syncthreads();
    }
    const float n = s_red[0];

    out[OFF_NECS + k] = necs;
    s_den[k] = (necs + EPSV) / (n + (float)KC * EPSV) * n;
    __syncthreads();

    #pragma unroll 4
    for (int i = 0; i < 64; ++i) {
        const int e = k + 1024 * i;             // coalesced over 65536 elements
        const float s  = out[OFF_NEW + e];      // raw cluster sum
        const float ew = DECAY * ema_w[e] + ONEM * s;
        out[OFF_NEW + e] = ew;                  // new_ew
        out[OFF_NCB + e] = ew / s_den[e >> 6];  // new_codebook
    }
    if (k == 0) out[OFF_LOSS] = 0.25f * out[OFF_LOSS] * (1.f / 4194304.f);
}

extern "C" void kernel_launch(void* const* d_in, const int* in_sizes, int n_in,
                              void* d_out, int out_size, void* d_ws, size_t ws_size,
                              hipStream_t stream) {
    const float* z   = (const float*)d_in[0];
    const float* cb  = (const float*)d_in[1];
    const float* ecs = (const float*)d_in[2];
    const float* ew  = (const float*)d_in[3];
    float* out = (float*)d_out;

    vq_prep <<<256,  256, 0, stream>>>(cb, out);
    vq_main <<<1024, 512, 0, stream>>>(z, cb, out + OFF_NCB, out);
    vq_final<<<1,   1024, 0, stream>>>(ecs, ew, out);
}

// Round 5
// 287.771 us; speedup vs baseline: 1.9284x; 1.9284x over previous
//
#include <hip/hip_runtime.h>

// Problem constants
#define KC   1024        // codebook size
#define DD   64          // code dim
#define NR   65536       // total rows (16*4096)

#define DECAY     0.99f
#define ONEM      0.01f
#define EPSV      1e-5f

// d_out layout (floats), in reference return order:
#define OFF_ZQ    0
#define OFF_LOSS  4194304
#define OFF_IDX   4194305
#define OFF_NCB   4259841
#define OFF_NECS  4325377
#define OFF_NEW   4326401

// Scratch aliases inside d_out (zeroed by prep, consumed+overwritten later):
//   cluster counts  -> OFF_NECS region (1024)
//   cluster sums    -> OFF_NEW region (65536)
//   sum-sq-error    -> OFF_LOSS (1)
//   ||c||^2 table   -> first 1024 floats of OFF_NCB region
// d_ws: first 1024 floats = stabilized denominator table (final_a -> final_b).

__global__ void vq_prep(const float* __restrict__ cb, float* __restrict__ out) {
    int tid = blockIdx.x * blockDim.x + threadIdx.x;
    if (tid < 65536) out[OFF_NEW + tid] = 0.0f;          // cluster sums
    if (tid < 1024) {
        out[OFF_NECS + tid] = 0.0f;                      // cluster counts
        const float4* c = reinterpret_cast<const float4*>(cb + tid * 64);
        float s = 0.f;
        #pragma unroll
        for (int j = 0; j < 16; ++j) {
            const float4 v = c[j];
            s += v.x*v.x + v.y*v.y + v.z*v.z + v.w*v.w;
        }
        out[OFF_NCB + tid] = s;                          // ||c_k||^2
    }
    if (tid == 0) out[OFF_LOSS] = 0.0f;                  // SSE accumulator
}

// 1024 blocks x 512 threads (8 waves). Each block owns 64 rows.
// lane (0..63) = row; wave (0..7) = 128-code chunk (16 codes per step).
// z tile in LDS (stride 68 -> 16B-aligned b128, conflict-free); codebook
// addresses are wave-uniform float4 loads (broadcast). Per dt-iteration:
// 1 ds_read_b128 + 16 uniform 16B loads feed 64 v_fmac.
// NOTE launch_bounds(512,4): VGPR cap 128. (512,8) capped at 64 and spilled
// (round-4 regression: scratch traffic +350MB through TCC).
__global__ __launch_bounds__(512, 4) void vq_main(const float* __restrict__ z,
                                                  const float* __restrict__ cb,
                                                  const float* __restrict__ cc,
                                                  float* __restrict__ out) {
    const int lane = threadIdx.x & 63;
    const int wid  = threadIdx.x >> 6;
    const int t    = threadIdx.x;

    __shared__ float s_zs[64 * 68];          // [row][d], stride 68 (17.4 KB)
    __shared__ float s_dist[8][64];
    __shared__ int   s_idx [8][64];
    __shared__ int   s_final[64];
    __shared__ float s_red[512];

    // Stage z tile: 2 float4s per thread, ds_write_b128.
    const float4* zb4 = reinterpret_cast<const float4*>(z) + (size_t)blockIdx.x * 1024;
    #pragma unroll
    for (int j = 0; j < 2; ++j) {
        const int f = t + 512 * j;           // float4 index in 64x64 tile
        const float4 v = zb4[f];
        const int r  = f >> 4;
        const int d0 = (f & 15) * 4;
        *reinterpret_cast<float4*>(&s_zs[r * 68 + d0]) = v;
    }
    __syncthreads();

    // Wave-uniform code-chunk base in an SGPR.
    const int kbase = __builtin_amdgcn_readfirstlane(wid) * 128;

    float bestd = 3.4e38f;
    int   bestk = kbase;
    for (int k0 = kbase; k0 < kbase + 128; k0 += 16) {
        const float* c0 = cb + (size_t)k0 * 64;
        float acc[16];
        #pragma unroll
        for (int j = 0; j < 16; ++j) acc[j] = 0.f;
        #pragma unroll
        for (int dt = 0; dt < 16; ++dt) {
            const float4 zv = *reinterpret_cast<const float4*>(&s_zs[lane * 68 + dt * 4]);
            #pragma unroll
            for (int j = 0; j < 16; ++j) {
                const float4 cv = *reinterpret_cast<const float4*>(c0 + j * 64 + dt * 4);
                acc[j] = fmaf(zv.x, cv.x, acc[j]);
                acc[j] = fmaf(zv.y, cv.y, acc[j]);
                acc[j] = fmaf(zv.z, cv.z, acc[j]);
                acc[j] = fmaf(zv.w, cv.w, acc[j]);
            }
        }
        // score = ||c||^2 - 2*dot (row-term constant over k -> same argmin).
        // Ascending code order + strict < == numpy first-min tiebreak.
        #pragma unroll
        for (int j = 0; j < 16; ++j) {
            const float s = fmaf(-2.f, acc[j], cc[k0 + j]);
            if (s < bestd) { bestd = s; bestk = k0 + j; }
        }
    }

    s_dist[wid][lane] = bestd;
    s_idx [wid][lane] = bestk;
    __syncthreads();

    if (wid == 0) {
        float bd = s_dist[0][lane];
        int   bk = s_idx [0][lane];
        #pragma unroll
        for (int w = 1; w < 8; ++w) {
            const float dw = s_dist[w][lane];
            if (dw < bd) { bd = dw; bk = s_idx[w][lane]; }  // waves ascend in code space
        }
        s_final[lane] = bk;
        const int row = blockIdx.x * 64 + lane;
        out[OFF_IDX + row] = (float)bk;
        atomicAdd(&out[OFF_NECS + bk], 1.0f);               // cluster count
    }
    __syncthreads();

    // Phase 2: coalesced z_q write + commitment SSE + cluster-sum atomics.
    float sse = 0.f;
    float4* qb = reinterpret_cast<float4*>(out + OFF_ZQ) + (size_t)blockIdx.x * 1024;
    const float4* cb4 = reinterpret_cast<const float4*>(cb);
    #pragma unroll
    for (int j = 0; j < 2; ++j) {
        const int f  = t + 512 * j;     // float4 index in block tile
        const int r  = f >> 4;          // row within tile
        const int fc = f & 15;          // float4 within row
        const int gk = s_final[r];
        const float4 zv = *reinterpret_cast<const float4*>(&s_zs[r * 68 + fc * 4]);
        const float4 cv = cb4[gk * 16 + fc];
        qb[f] = cv;                     // z_q_st == z_q numerically
        const float e0 = zv.x - cv.x, e1 = zv.y - cv.y;
        const float e2 = zv.z - cv.z, e3 = zv.w - cv.w;
        sse += e0*e0 + e1*e1 + e2*e2 + e3*e3;
        float* sp = out + OFF_NEW + gk * 64 + fc * 4;
        atomicAdd(sp + 0, zv.x);
        atomicAdd(sp + 1, zv.y);
        atomicAdd(sp + 2, zv.z);
        atomicAdd(sp + 3, zv.w);
    }

    s_red[t] = sse;
    __syncthreads();
    for (int off = 256; off > 0; off >>= 1) {
        if (t < off) s_red[t] += s_red[t + off];
        __syncthreads();
    }
    if (t == 0) atomicAdd(&out[OFF_LOSS], s_red[0]);
}

// One block, 1024 threads: EMA cluster-size update + n-reduction + den table.
__global__ __launch_bounds__(1024) void vq_final_a(const float* __restrict__ ema_cs,
                                                   float* __restrict__ out,
                                                   float* __restrict__ den) {
    const int k = threadIdx.x;
    const float cnt  = out[OFF_NECS + k];
    const float necs = DECAY * ema_cs[k] + ONEM * cnt;

    __shared__ float s_red[1024];
    s_red[k] = necs;
    __syncthreads();
    for (int off = 512; off > 0; off >>= 1) {
        if (k < off) s_red[k] += s_red[k + off];
        __syncthreads();
    }
    const float n = s_red[0];

    out[OFF_NECS + k] = necs;
    den[k] = (necs + EPSV) / (n + (float)KC * EPSV) * n;
    if (k == 0) out[OFF_LOSS] = 0.25f * out[OFF_LOSS] * (1.f / 4194304.f);
}

// 64 blocks x 1024 threads: EMA w update + codebook normalization.
__global__ __launch_bounds__(1024) void vq_final_b(const float* __restrict__ ema_w,
                                                   const float* __restrict__ den,
                                                   float* __restrict__ out) {
    const int e = blockIdx.x * 1024 + threadIdx.x;      // 0..65535, coalesced
    const float s  = out[OFF_NEW + e];                  // raw cluster sum
    const float ew = DECAY * ema_w[e] + ONEM * s;
    out[OFF_NEW + e] = ew;                              // new_ew
    out[OFF_NCB + e] = ew / den[e >> 6];                // new_codebook
}

extern "C" void kernel_launch(void* const* d_in, const int* in_sizes, int n_in,
                              void* d_out, int out_size, void* d_ws, size_t ws_size,
                              hipStream_t stream) {
    const float* z   = (const float*)d_in[0];
    const float* cb  = (const float*)d_in[1];
    const float* ecs = (const float*)d_in[2];
    const float* ew  = (const float*)d_in[3];
    float* out = (float*)d_out;
    float* den = (float*)d_ws;      // 1024 floats of scratch

    vq_prep   <<<256,  256, 0, stream>>>(cb, out);
    vq_main   <<<1024, 512, 0, stream>>>(z, cb, out + OFF_NCB, out);
    vq_final_a<<<1,   1024, 0, stream>>>(ecs, out, den);
    vq_final_b<<<64,  1024, 0, stream>>>(ew, den, out);
}